// Round 5
// baseline (288.735 us; speedup 1.0000x reference)
//
#include <hip/hip_runtime.h>
#include <hip/hip_bf16.h>

// N = 50000, E = 800000, F_IN = F_OUT = 128.
// Pipeline: CSR build (int atomics, u32 packed meta) -> XCD-sliced bf16
// weighted-mean aggregation (gathers L2-resident per slice) -> MFMA bf16
// GEMM with fragment-packed weights (no LDS) + bias + ReLU.

#define SCAN_CHUNK 1024
#define NSLICE 4     // feature slices (32 features = 64 B per node per slice)
#define FSL 32       // features per slice
#define RPW 16       // rows per wave in agg

typedef __attribute__((ext_vector_type(8))) short bf16x8;
typedef __attribute__((ext_vector_type(8))) unsigned short ushort8;
typedef __attribute__((ext_vector_type(4))) float f32x4;

__device__ __forceinline__ unsigned short f2bf(float f) {
    unsigned int u = __float_as_uint(f);
    unsigned int r = (u + 0x7fffu + ((u >> 16) & 1u)) >> 16;
    return (unsigned short)r;
}

// ---------------------------------------------------------------------------
// x[N][128] fp32 -> xs[slice][N][32] bf16 (slice-major for L2 residency).
// Thread i: sl = i/(N*4), n = (i%(N*4))>>2, q = i&3 -> features sl*32+q*8..+7.
// ---------------------------------------------------------------------------
__global__ __launch_bounds__(256) void xcvt_kernel(
    const float* __restrict__ x, unsigned short* __restrict__ xs, int N) {
    int i = blockIdx.x * 256 + threadIdx.x;
    if (i >= N * 16) return;
    int sl  = i / (N * 4);
    int rem = i - sl * N * 4;
    int n   = rem >> 2;
    int q   = rem & 3;
    const float4* xp = (const float4*)(x + (size_t)n * 128 + sl * FSL + q * 8);
    float4 v0 = xp[0];
    float4 v1 = xp[1];
    ushort8 o;
    o[0] = f2bf(v0.x); o[1] = f2bf(v0.y); o[2] = f2bf(v0.z); o[3] = f2bf(v0.w);
    o[4] = f2bf(v1.x); o[5] = f2bf(v1.y); o[6] = f2bf(v1.z); o[7] = f2bf(v1.w);
    *(ushort8*)(xs + ((size_t)sl * N + n) * FSL + q * 8) = o;
}

// ---------------------------------------------------------------------------
// Pack weights into MFMA B-fragment order.
// B_h[k][c] (K=256: rows 0-127 = w_l_h^T, 128-255 = w_r_h^T), fragment
// layout for mfma_f32_16x16x32_bf16: lane l holds B[k=32*kk+8*(l>>4)+j][c=16*nr+(l&15)].
// Bfrag index = ((h*64 + kk*8 + nr)*64 + l)*8 + j.
// ---------------------------------------------------------------------------
__global__ __launch_bounds__(256) void bfrag_kernel(
    const float* __restrict__ wpl, const float* __restrict__ wpr,
    const float* __restrict__ wnl, const float* __restrict__ wnr,
    unsigned short* __restrict__ Bfrag) {
    int tid = blockIdx.x * 256 + threadIdx.x;   // 0..8191
    int l  = tid & 63;
    int nr = (tid >> 6) & 7;
    int kk = (tid >> 9) & 7;
    int h  = tid >> 12;
    const float* wl = h ? wnl : wpl;
    const float* wr = h ? wnr : wpr;
    int c  = nr * 16 + (l & 15);
    int k0 = kk * 32 + (l >> 4) * 8;
    ushort8 o;
#pragma unroll
    for (int j = 0; j < 8; ++j) {
        int k = k0 + j;
        float v = (k < 128) ? wl[c * 128 + k] : wr[c * 128 + (k - 128)];
        o[j] = f2bf(v);
    }
    *(ushort8*)(Bfrag + (size_t)tid * 8) = o;
}

// ---------------------------------------------------------------------------
// CSR build pass 1: per-(sign,dst) edge counts.
// ---------------------------------------------------------------------------
__global__ __launch_bounds__(256) void count_kernel(
    const int* __restrict__ ei, const float* __restrict__ attr,
    int* __restrict__ counts, int E, int N) {
    int e = blockIdx.x * 256 + threadIdx.x;
    if (e >= E) return;
    float w = attr[e];
    if (w == 0.f) return;
    int h = (w > 0.f) ? 0 : 1;
    int dst = ei[E + e];
    atomicAdd(&counts[h * N + dst], 1);
}

// ---------------------------------------------------------------------------
// Exclusive scan over counts[0..n): chunked (1024/block).
// ---------------------------------------------------------------------------
__global__ __launch_bounds__(256) void scan_k1(
    const int* __restrict__ counts, int* __restrict__ partial, int n) {
    __shared__ int sd[256];
    int b = blockIdx.x, t = threadIdx.x;
    int idx = b * SCAN_CHUNK + t * 4;
    int s = 0;
#pragma unroll
    for (int j = 0; j < 4; ++j) { int i = idx + j; if (i < n) s += counts[i]; }
    sd[t] = s;
    __syncthreads();
    for (int off = 128; off > 0; off >>= 1) {
        if (t < off) sd[t] += sd[t + off];
        __syncthreads();
    }
    if (t == 0) partial[b] = sd[0];
}

__global__ __launch_bounds__(128) void scan_k2(
    const int* __restrict__ partial, int* __restrict__ base, int nb) {
    __shared__ int sd[128];
    int t = threadIdx.x;
    int own = (t < nb) ? partial[t] : 0;
    sd[t] = own;
    __syncthreads();
    for (int off = 1; off < 128; off <<= 1) {
        int v = (t >= off) ? sd[t - off] : 0;
        __syncthreads();
        sd[t] += v;
        __syncthreads();
    }
    if (t < nb) base[t] = sd[t] - own;   // exclusive
}

__global__ __launch_bounds__(256) void scan_k3(
    const int* __restrict__ counts, const int* __restrict__ base,
    int* __restrict__ offs, int* __restrict__ cursor, int n) {
    __shared__ int sd[256];
    int b = blockIdx.x, t = threadIdx.x;
    int idx = b * SCAN_CHUNK + t * 4;
    int c[4]; int s = 0;
#pragma unroll
    for (int j = 0; j < 4; ++j) { int i = idx + j; c[j] = (i < n) ? counts[i] : 0; s += c[j]; }
    sd[t] = s;
    __syncthreads();
    for (int off = 1; off < 256; off <<= 1) {   // inclusive Hillis-Steele
        int v = (t >= off) ? sd[t - off] : 0;
        __syncthreads();
        sd[t] += v;
        __syncthreads();
    }
    int run = base[b] + sd[t] - s;
#pragma unroll
    for (int j = 0; j < 4; ++j) {
        int i = idx + j;
        if (i < n) { offs[i] = run; cursor[i] = run; run += c[j]; }
    }
}

// ---------------------------------------------------------------------------
// CSR build pass 2: scatter packed meta = src (16b) | bf16(|w|) (16b).
// ---------------------------------------------------------------------------
__global__ __launch_bounds__(256) void scatter_kernel(
    const int* __restrict__ ei, const float* __restrict__ attr,
    int* __restrict__ cursor, unsigned* __restrict__ meta, int E, int N) {
    int e = blockIdx.x * 256 + threadIdx.x;
    if (e >= E) return;
    float w = attr[e];
    if (w == 0.f) return;
    int h = (w > 0.f) ? 0 : 1;
    int dst = ei[E + e];
    int slot = atomicAdd(&cursor[h * N + dst], 1);
    unsigned m = (unsigned)ei[e] | ((unsigned)f2bf(fabsf(w)) << 16);
    __builtin_nontemporal_store(m, &meta[slot]);
}

// ---------------------------------------------------------------------------
// Sliced aggregation. blockIdx%4 = feature slice (3.2 MB, L2-resident on its
// XCDs via round-robin dispatch). Wave handles RPW rows; lanes: g = edge
// group (4 edges/batch), fp = feature pair (16 lanes x 4B = one 64B line per
// edge). Cross-group shfl_xor reduce, mean fold, NT store of bf16 pairs.
// ---------------------------------------------------------------------------
__global__ __launch_bounds__(256) void agg_kernel(
    const unsigned short* __restrict__ xs, const unsigned* __restrict__ meta,
    const int* __restrict__ counts, const int* __restrict__ offs,
    unsigned short* __restrict__ mh, int twoN, int N) {
    const int slice = blockIdx.x & (NSLICE - 1);
    const int bsl   = blockIdx.x >> 2;
    const int wv    = threadIdx.x >> 6;
    const int lane  = threadIdx.x & 63;
    const int g     = lane >> 4;     // edge group 0..3
    const int fp    = lane & 15;     // feature pair within slice
    const unsigned short* xsl = xs + (size_t)slice * N * FSL;
    const int rbase = (bsl * 4 + wv) * RPW;

    for (int rr = 0; rr < RPW; ++rr) {
        const int r = rbase + rr;
        if (r >= twoN) return;
        const int cn  = counts[r];
        const int beg = offs[r];
        float a0 = 0.f, a1 = 0.f;
        for (int j0 = 0; j0 < cn; j0 += 4) {
            const int jj = j0 + g;
            unsigned m = 0;
            if (jj < cn) m = __builtin_nontemporal_load(&meta[beg + jj]);
            const float w = __uint_as_float(m & 0xffff0000u);
            const unsigned src = m & 0xffffu;
            const unsigned v = *(const unsigned*)(xsl + (size_t)src * FSL + 2 * fp);
            a0 = fmaf(__uint_as_float(v << 16), w, a0);
            a1 = fmaf(__uint_as_float(v & 0xffff0000u), w, a1);
        }
        a0 += __shfl_xor(a0, 16, 64);
        a0 += __shfl_xor(a0, 32, 64);
        a1 += __shfl_xor(a1, 16, 64);
        a1 += __shfl_xor(a1, 32, 64);
        if (g == 0) {
            const float inv = 1.f / fmaxf((float)cn, 1.f);
            unsigned p = ((unsigned)f2bf(a1 * inv) << 16) | (unsigned)f2bf(a0 * inv);
            __builtin_nontemporal_store(
                p, (unsigned*)(mh + (size_t)r * 128 + slice * FSL + 2 * fp));
        }
    }
}

// ---------------------------------------------------------------------------
// Output GEMM via MFMA. grid = (ceil(N/128), 2), block 256 (4 waves).
// Wave w computes rows m0 = bx*128 + w*32 (2 M-frags), all 128 cols of its
// half. K=256: kk 0..3 read mean_h (row-major mh), kk 4..7 read x from the
// sliced xs layout (8-feature A-chunks never cross a 32-feature slice).
// B-frags from fragment-packed global (L2-resident). No LDS, no barriers.
// ---------------------------------------------------------------------------
__global__ __launch_bounds__(256) void out_mfma(
    const unsigned short* __restrict__ mh, const unsigned short* __restrict__ xs,
    const unsigned short* __restrict__ Bfrag,
    const float* __restrict__ bpos, const float* __restrict__ bneg,
    float* __restrict__ out, int N) {
    const int h  = blockIdx.y;
    const int l  = threadIdx.x & 63;
    const int wv = threadIdx.x >> 6;
    const int m0 = blockIdx.x * 128 + wv * 32;
    const int lm = l & 15;
    const int lk = l >> 4;

    const unsigned short* Am = mh + (size_t)h * N * 128;
    const bf16x8* Bf = (const bf16x8*)Bfrag + (size_t)h * 4096;

    f32x4 acc[2][8];
#pragma unroll
    for (int mr = 0; mr < 2; ++mr)
#pragma unroll
        for (int nr = 0; nr < 8; ++nr)
            acc[mr][nr] = (f32x4){0.f, 0.f, 0.f, 0.f};

    int r0 = m0 + lm;       if (r0 > N - 1) r0 = N - 1;
    int r1 = m0 + 16 + lm;  if (r1 > N - 1) r1 = N - 1;

#pragma unroll
    for (int kk = 0; kk < 8; ++kk) {
        bf16x8 a0, a1;
        if (kk < 4) {
            const int kloc = kk * 32 + lk * 8;
            a0 = *(const bf16x8*)(Am + (size_t)r0 * 128 + kloc);
            a1 = *(const bf16x8*)(Am + (size_t)r1 * 128 + kloc);
        } else {
            const size_t sbase = (size_t)(kk & 3) * N * FSL + lk * 8;
            a0 = *(const bf16x8*)(xs + sbase + (size_t)r0 * FSL);
            a1 = *(const bf16x8*)(xs + sbase + (size_t)r1 * FSL);
        }
        const bf16x8* bk = Bf + kk * 8 * 64;
#pragma unroll
        for (int nr = 0; nr < 8; ++nr) {
            bf16x8 b = bk[nr * 64 + l];
            acc[0][nr] = __builtin_amdgcn_mfma_f32_16x16x32_bf16(a0, b, acc[0][nr], 0, 0, 0);
            acc[1][nr] = __builtin_amdgcn_mfma_f32_16x16x32_bf16(a1, b, acc[1][nr], 0, 0, 0);
        }
    }

    const float* bb = (h == 0) ? bpos : bneg;
#pragma unroll
    for (int nr = 0; nr < 8; ++nr) {
        const float bc = bb[nr * 16 + lm];
#pragma unroll
        for (int mr = 0; mr < 2; ++mr) {
#pragma unroll
            for (int rr = 0; rr < 4; ++rr) {
                const int row = m0 + mr * 16 + lk * 4 + rr;
                if (row < N)
                    out[(size_t)row * 256 + h * 128 + nr * 16 + lm] =
                        fmaxf(acc[mr][nr][rr] + bc, 0.f);
            }
        }
    }
}

// ---------------------------------------------------------------------------
extern "C" void kernel_launch(void* const* d_in, const int* in_sizes, int n_in,
                              void* d_out, int out_size, void* d_ws, size_t ws_size,
                              hipStream_t stream) {
    const float* x    = (const float*)d_in[0];
    const int*   ei   = (const int*)d_in[1];
    const float* attr = (const float*)d_in[2];
    const float* wpl  = (const float*)d_in[3];
    const float* wpr  = (const float*)d_in[4];
    const float* bpos = (const float*)d_in[5];
    const float* wnl  = (const float*)d_in[6];
    const float* wnr  = (const float*)d_in[7];
    const float* bneg = (const float*)d_in[8];
    float* out = (float*)d_out;

    const int N = in_sizes[0] / 128;   // 50000
    const int E = in_sizes[2];         // 800000
    const int twoN = 2 * N;

    // Workspace layout:
    //   mh     ushort [2N][128]      bf16 per-sign means (already divided)
    //   xs     ushort [4][N][32]     bf16 features, slice-major
    //   Bfrag  ushort [2][4096][8]   fragment-packed weights
    //   meta   u32    [E]            packed (src | bf16|w|<<16) CSR records
    //   counts,offs,cursor int [2N]
    //   partial,base int [128]
    unsigned short* mh    = (unsigned short*)d_ws;
    unsigned short* xs    = mh + (size_t)twoN * 128;
    unsigned short* Bfrag = xs + (size_t)N * 128;
    unsigned* meta = (unsigned*)(Bfrag + 65536);
    int* counts  = (int*)(meta + E);
    int* offs    = counts + twoN;
    int* cursor  = offs + twoN;
    int* partial = cursor + twoN;
    int* sbase   = partial + 128;

    const int nchunk = (twoN + SCAN_CHUNK - 1) / SCAN_CHUNK;   // 98 (<=128)

    hipMemsetAsync(counts, 0, (size_t)twoN * sizeof(int), stream);

    xcvt_kernel<<<(N * 16 + 255) / 256, 256, 0, stream>>>(x, xs, N);
    bfrag_kernel<<<32, 256, 0, stream>>>(wpl, wpr, wnl, wnr, Bfrag);
    count_kernel<<<(E + 255) / 256, 256, 0, stream>>>(ei, attr, counts, E, N);
    scan_k1<<<nchunk, 256, 0, stream>>>(counts, partial, twoN);
    scan_k2<<<1, 128, 0, stream>>>(partial, sbase, nchunk);
    scan_k3<<<nchunk, 256, 0, stream>>>(counts, sbase, offs, cursor, twoN);
    scatter_kernel<<<(E + 255) / 256, 256, 0, stream>>>(ei, attr, cursor, meta, E, N);
    const int rows_per_blk = 4 * RPW;                           // 64
    const int blk_per_sl   = (twoN + rows_per_blk - 1) / rows_per_blk;
    agg_kernel<<<blk_per_sl * NSLICE, 256, 0, stream>>>(xs, meta, counts, offs, mh, twoN, N);
    out_mfma<<<dim3((N + 127) / 128, 2), 256, 0, stream>>>(mh, xs, Bfrag, bpos, bneg, out, N);
}

// Round 6
// 247.089 us; speedup vs baseline: 1.1685x; 1.1685x over previous
//
#include <hip/hip_runtime.h>
#include <hip/hip_bf16.h>

// N = 50000, E = 800000, F_IN = F_OUT = 128.
// Pipeline: CSR build (int atomics, u32 packed meta) -> XCD-sliced bf16
// weighted-mean aggregation (L2-resident gathers + one wave per row for max
// TLP, 8 edges in flight) -> MFMA bf16 GEMM with fragment-packed weights.

#define SCAN_CHUNK 1024
#define NSLICE 4     // feature slices (32 features = 64 B per node per slice)
#define FSL 32       // features per slice

typedef __attribute__((ext_vector_type(8))) short bf16x8;
typedef __attribute__((ext_vector_type(8))) unsigned short ushort8;
typedef __attribute__((ext_vector_type(4))) float f32x4;

__device__ __forceinline__ unsigned short f2bf(float f) {
    unsigned int u = __float_as_uint(f);
    unsigned int r = (u + 0x7fffu + ((u >> 16) & 1u)) >> 16;
    return (unsigned short)r;
}

// ---------------------------------------------------------------------------
// x[N][128] fp32 -> xs[slice][N][32] bf16 (slice-major for L2 residency).
// ---------------------------------------------------------------------------
__global__ __launch_bounds__(256) void xcvt_kernel(
    const float* __restrict__ x, unsigned short* __restrict__ xs, int N) {
    int i = blockIdx.x * 256 + threadIdx.x;
    if (i >= N * 16) return;
    int sl  = i / (N * 4);
    int rem = i - sl * N * 4;
    int n   = rem >> 2;
    int q   = rem & 3;
    const float4* xp = (const float4*)(x + (size_t)n * 128 + sl * FSL + q * 8);
    float4 v0 = xp[0];
    float4 v1 = xp[1];
    ushort8 o;
    o[0] = f2bf(v0.x); o[1] = f2bf(v0.y); o[2] = f2bf(v0.z); o[3] = f2bf(v0.w);
    o[4] = f2bf(v1.x); o[5] = f2bf(v1.y); o[6] = f2bf(v1.z); o[7] = f2bf(v1.w);
    *(ushort8*)(xs + ((size_t)sl * N + n) * FSL + q * 8) = o;
}

// ---------------------------------------------------------------------------
// Pack weights into MFMA B-fragment order.
// B_h[k][c] (K=256: rows 0-127 = w_l_h^T, 128-255 = w_r_h^T), fragment
// layout for mfma_f32_16x16x32_bf16: lane l holds B[k=32*kk+8*(l>>4)+j][c=16*nr+(l&15)].
// ---------------------------------------------------------------------------
__global__ __launch_bounds__(256) void bfrag_kernel(
    const float* __restrict__ wpl, const float* __restrict__ wpr,
    const float* __restrict__ wnl, const float* __restrict__ wnr,
    unsigned short* __restrict__ Bfrag) {
    int tid = blockIdx.x * 256 + threadIdx.x;   // 0..8191
    int l  = tid & 63;
    int nr = (tid >> 6) & 7;
    int kk = (tid >> 9) & 7;
    int h  = tid >> 12;
    const float* wl = h ? wnl : wpl;
    const float* wr = h ? wnr : wpr;
    int c  = nr * 16 + (l & 15);
    int k0 = kk * 32 + (l >> 4) * 8;
    ushort8 o;
#pragma unroll
    for (int j = 0; j < 8; ++j) {
        int k = k0 + j;
        float v = (k < 128) ? wl[c * 128 + k] : wr[c * 128 + (k - 128)];
        o[j] = f2bf(v);
    }
    *(ushort8*)(Bfrag + (size_t)tid * 8) = o;
}

// ---------------------------------------------------------------------------
// CSR build pass 1: per-(sign,dst) edge counts.
// ---------------------------------------------------------------------------
__global__ __launch_bounds__(256) void count_kernel(
    const int* __restrict__ ei, const float* __restrict__ attr,
    int* __restrict__ counts, int E, int N) {
    int e = blockIdx.x * 256 + threadIdx.x;
    if (e >= E) return;
    float w = attr[e];
    if (w == 0.f) return;
    int h = (w > 0.f) ? 0 : 1;
    int dst = ei[E + e];
    atomicAdd(&counts[h * N + dst], 1);
}

// ---------------------------------------------------------------------------
// Exclusive scan over counts[0..n): chunked (1024/block).
// ---------------------------------------------------------------------------
__global__ __launch_bounds__(256) void scan_k1(
    const int* __restrict__ counts, int* __restrict__ partial, int n) {
    __shared__ int sd[256];
    int b = blockIdx.x, t = threadIdx.x;
    int idx = b * SCAN_CHUNK + t * 4;
    int s = 0;
#pragma unroll
    for (int j = 0; j < 4; ++j) { int i = idx + j; if (i < n) s += counts[i]; }
    sd[t] = s;
    __syncthreads();
    for (int off = 128; off > 0; off >>= 1) {
        if (t < off) sd[t] += sd[t + off];
        __syncthreads();
    }
    if (t == 0) partial[b] = sd[0];
}

__global__ __launch_bounds__(128) void scan_k2(
    const int* __restrict__ partial, int* __restrict__ base, int nb) {
    __shared__ int sd[128];
    int t = threadIdx.x;
    int own = (t < nb) ? partial[t] : 0;
    sd[t] = own;
    __syncthreads();
    for (int off = 1; off < 128; off <<= 1) {
        int v = (t >= off) ? sd[t - off] : 0;
        __syncthreads();
        sd[t] += v;
        __syncthreads();
    }
    if (t < nb) base[t] = sd[t] - own;   // exclusive
}

__global__ __launch_bounds__(256) void scan_k3(
    const int* __restrict__ counts, const int* __restrict__ base,
    int* __restrict__ offs, int* __restrict__ cursor, int n) {
    __shared__ int sd[256];
    int b = blockIdx.x, t = threadIdx.x;
    int idx = b * SCAN_CHUNK + t * 4;
    int c[4]; int s = 0;
#pragma unroll
    for (int j = 0; j < 4; ++j) { int i = idx + j; c[j] = (i < n) ? counts[i] : 0; s += c[j]; }
    sd[t] = s;
    __syncthreads();
    for (int off = 1; off < 256; off <<= 1) {   // inclusive Hillis-Steele
        int v = (t >= off) ? sd[t - off] : 0;
        __syncthreads();
        sd[t] += v;
        __syncthreads();
    }
    int run = base[b] + sd[t] - s;
#pragma unroll
    for (int j = 0; j < 4; ++j) {
        int i = idx + j;
        if (i < n) { offs[i] = run; cursor[i] = run; run += c[j]; }
    }
}

// ---------------------------------------------------------------------------
// CSR build pass 2: scatter packed meta = src (16b) | bf16(|w|) (16b).
// ---------------------------------------------------------------------------
__global__ __launch_bounds__(256) void scatter_kernel(
    const int* __restrict__ ei, const float* __restrict__ attr,
    int* __restrict__ cursor, unsigned* __restrict__ meta, int E, int N) {
    int e = blockIdx.x * 256 + threadIdx.x;
    if (e >= E) return;
    float w = attr[e];
    if (w == 0.f) return;
    int h = (w > 0.f) ? 0 : 1;
    int dst = ei[E + e];
    int slot = atomicAdd(&cursor[h * N + dst], 1);
    meta[slot] = (unsigned)ei[e] | ((unsigned)f2bf(fabsf(w)) << 16);
}

// ---------------------------------------------------------------------------
// Sliced aggregation, one wave per (row, slice). blockIdx%4 = slice (3.2 MB,
// L2-resident on its XCDs via round-robin dispatch). Within a wave: g = edge
// slot (4 edges concurrent), fp = feature pair (16 lanes x 4B = 64B line per
// edge); unroll 2 -> 8 gathers in flight. shfl_xor reduce across slots, mean
// fold, coalesced bf16 store. 400K waves total for TLP.
// ---------------------------------------------------------------------------
__global__ __launch_bounds__(256) void agg_kernel(
    const unsigned short* __restrict__ xs, const unsigned* __restrict__ meta,
    const int* __restrict__ counts, const int* __restrict__ offs,
    unsigned short* __restrict__ mh, int twoN, int N) {
    const int slice = blockIdx.x & (NSLICE - 1);
    const int rb    = blockIdx.x >> 2;
    const int wv    = threadIdx.x >> 6;
    const int r     = rb * 4 + wv;
    if (r >= twoN) return;
    const int lane = threadIdx.x & 63;
    const int g    = lane >> 4;     // edge slot 0..3
    const int fp   = lane & 15;     // feature pair within slice
    const unsigned short* xsl = xs + (size_t)slice * N * FSL;

    const int cn  = counts[r];
    const int beg = offs[r];
    float a0 = 0.f, a1 = 0.f;
    for (int j0 = 0; j0 < cn; j0 += 8) {
        const int j1 = j0 + g;
        const int j2 = j0 + 4 + g;
        unsigned m1 = 0, m2 = 0;
        if (j1 < cn) m1 = meta[beg + j1];
        if (j2 < cn) m2 = meta[beg + j2];
        const unsigned v1 = *(const unsigned*)(xsl + (size_t)(m1 & 0xffffu) * FSL + 2 * fp);
        const unsigned v2 = *(const unsigned*)(xsl + (size_t)(m2 & 0xffffu) * FSL + 2 * fp);
        const float w1 = __uint_as_float(m1 & 0xffff0000u);
        const float w2 = __uint_as_float(m2 & 0xffff0000u);
        a0 = fmaf(__uint_as_float(v1 << 16), w1, a0);
        a1 = fmaf(__uint_as_float(v1 & 0xffff0000u), w1, a1);
        a0 = fmaf(__uint_as_float(v2 << 16), w2, a0);
        a1 = fmaf(__uint_as_float(v2 & 0xffff0000u), w2, a1);
    }
    a0 += __shfl_xor(a0, 16, 64);
    a0 += __shfl_xor(a0, 32, 64);
    a1 += __shfl_xor(a1, 16, 64);
    a1 += __shfl_xor(a1, 32, 64);
    if (g == 0) {
        const float inv = 1.f / fmaxf((float)cn, 1.f);
        unsigned p = ((unsigned)f2bf(a1 * inv) << 16) | (unsigned)f2bf(a0 * inv);
        *(unsigned*)(mh + (size_t)r * 128 + slice * FSL + 2 * fp) = p;
    }
}

// ---------------------------------------------------------------------------
// Output GEMM via MFMA. grid = (ceil(N/128), 2), block 256 (4 waves).
// K=256: kk 0..3 read mean_h (row-major mh), kk 4..7 read x from the sliced
// xs layout (8-feature A-chunks never cross a 32-feature slice). B-frags
// from fragment-packed global (L2-resident). No LDS, no barriers.
// ---------------------------------------------------------------------------
__global__ __launch_bounds__(256) void out_mfma(
    const unsigned short* __restrict__ mh, const unsigned short* __restrict__ xs,
    const unsigned short* __restrict__ Bfrag,
    const float* __restrict__ bpos, const float* __restrict__ bneg,
    float* __restrict__ out, int N) {
    const int h  = blockIdx.y;
    const int l  = threadIdx.x & 63;
    const int wv = threadIdx.x >> 6;
    const int m0 = blockIdx.x * 128 + wv * 32;
    const int lm = l & 15;
    const int lk = l >> 4;

    const unsigned short* Am = mh + (size_t)h * N * 128;
    const bf16x8* Bf = (const bf16x8*)Bfrag + (size_t)h * 4096;

    f32x4 acc[2][8];
#pragma unroll
    for (int mr = 0; mr < 2; ++mr)
#pragma unroll
        for (int nr = 0; nr < 8; ++nr)
            acc[mr][nr] = (f32x4){0.f, 0.f, 0.f, 0.f};

    int r0 = m0 + lm;       if (r0 > N - 1) r0 = N - 1;
    int r1 = m0 + 16 + lm;  if (r1 > N - 1) r1 = N - 1;

#pragma unroll
    for (int kk = 0; kk < 8; ++kk) {
        bf16x8 a0, a1;
        if (kk < 4) {
            const int kloc = kk * 32 + lk * 8;
            a0 = *(const bf16x8*)(Am + (size_t)r0 * 128 + kloc);
            a1 = *(const bf16x8*)(Am + (size_t)r1 * 128 + kloc);
        } else {
            const size_t sbase = (size_t)(kk & 3) * N * FSL + lk * 8;
            a0 = *(const bf16x8*)(xs + sbase + (size_t)r0 * FSL);
            a1 = *(const bf16x8*)(xs + sbase + (size_t)r1 * FSL);
        }
        const bf16x8* bk = Bf + kk * 8 * 64;
#pragma unroll
        for (int nr = 0; nr < 8; ++nr) {
            bf16x8 b = bk[nr * 64 + l];
            acc[0][nr] = __builtin_amdgcn_mfma_f32_16x16x32_bf16(a0, b, acc[0][nr], 0, 0, 0);
            acc[1][nr] = __builtin_amdgcn_mfma_f32_16x16x32_bf16(a1, b, acc[1][nr], 0, 0, 0);
        }
    }

    const float* bb = (h == 0) ? bpos : bneg;
#pragma unroll
    for (int nr = 0; nr < 8; ++nr) {
        const float bc = bb[nr * 16 + lm];
#pragma unroll
        for (int mr = 0; mr < 2; ++mr) {
#pragma unroll
            for (int rr = 0; rr < 4; ++rr) {
                const int row = m0 + mr * 16 + lk * 4 + rr;
                if (row < N)
                    out[(size_t)row * 256 + h * 128 + nr * 16 + lm] =
                        fmaxf(acc[mr][nr][rr] + bc, 0.f);
            }
        }
    }
}

// ---------------------------------------------------------------------------
extern "C" void kernel_launch(void* const* d_in, const int* in_sizes, int n_in,
                              void* d_out, int out_size, void* d_ws, size_t ws_size,
                              hipStream_t stream) {
    const float* x    = (const float*)d_in[0];
    const int*   ei   = (const int*)d_in[1];
    const float* attr = (const float*)d_in[2];
    const float* wpl  = (const float*)d_in[3];
    const float* wpr  = (const float*)d_in[4];
    const float* bpos = (const float*)d_in[5];
    const float* wnl  = (const float*)d_in[6];
    const float* wnr  = (const float*)d_in[7];
    const float* bneg = (const float*)d_in[8];
    float* out = (float*)d_out;

    const int N = in_sizes[0] / 128;   // 50000
    const int E = in_sizes[2];         // 800000
    const int twoN = 2 * N;

    // Workspace layout:
    //   mh     ushort [2N][128]      bf16 per-sign means (already divided)
    //   xs     ushort [4][N][32]     bf16 features, slice-major
    //   Bfrag  ushort [2][4096][8]   fragment-packed weights
    //   meta   u32    [E]            packed (src | bf16|w|<<16) CSR records
    //   counts,offs,cursor int [2N]
    //   partial,base int [128]
    unsigned short* mh    = (unsigned short*)d_ws;
    unsigned short* xs    = mh + (size_t)twoN * 128;
    unsigned short* Bfrag = xs + (size_t)N * 128;
    unsigned* meta = (unsigned*)(Bfrag + 65536);
    int* counts  = (int*)(meta + E);
    int* offs    = counts + twoN;
    int* cursor  = offs + twoN;
    int* partial = cursor + twoN;
    int* sbase   = partial + 128;

    const int nchunk = (twoN + SCAN_CHUNK - 1) / SCAN_CHUNK;   // 98 (<=128)

    hipMemsetAsync(counts, 0, (size_t)twoN * sizeof(int), stream);

    xcvt_kernel<<<(N * 16 + 255) / 256, 256, 0, stream>>>(x, xs, N);
    bfrag_kernel<<<32, 256, 0, stream>>>(wpl, wpr, wnl, wnr, Bfrag);
    count_kernel<<<(E + 255) / 256, 256, 0, stream>>>(ei, attr, counts, E, N);
    scan_k1<<<nchunk, 256, 0, stream>>>(counts, partial, twoN);
    scan_k2<<<1, 128, 0, stream>>>(partial, sbase, nchunk);
    scan_k3<<<nchunk, 256, 0, stream>>>(counts, sbase, offs, cursor, twoN);
    scatter_kernel<<<(E + 255) / 256, 256, 0, stream>>>(ei, attr, cursor, meta, E, N);
    agg_kernel<<<((twoN + 3) / 4) * NSLICE, 256, 0, stream>>>(xs, meta, counts, offs, mh, twoN, N);
    out_mfma<<<dim3((N + 127) / 128, 2), 256, 0, stream>>>(mh, xs, Bfrag, bpos, bneg, out, N);
}

// Round 7
// 167.006 us; speedup vs baseline: 1.7289x; 1.4795x over previous
//
#include <hip/hip_runtime.h>
#include <hip/hip_bf16.h>

// N = 50000, E = 800000, F_IN = F_OUT = 128.
// Pipeline: prep (bf16 slice-cvt + edge counts + weight frag-pack) -> scan ->
// scatter (u32 packed meta) -> XCD-sliced aggregation (8 lanes x 8B = one
// 64B slice-row per edge, 4-deep edge pipeline per group, no shfl) ->
// MFMA bf16 GEMM with fragment-packed weights.

#define SCAN_CHUNK 1024
#define NSLICE 4     // feature slices (32 features = 64 B per node per slice)
#define FSL 32       // features per slice

typedef __attribute__((ext_vector_type(8))) short bf16x8;
typedef __attribute__((ext_vector_type(8))) unsigned short ushort8;
typedef __attribute__((ext_vector_type(4))) float f32x4;

__device__ __forceinline__ unsigned short f2bf(float f) {
    unsigned int u = __float_as_uint(f);
    unsigned int r = (u + 0x7fffu + ((u >> 16) & 1u)) >> 16;
    return (unsigned short)r;
}
__device__ __forceinline__ float bflo(unsigned u) { return __uint_as_float(u << 16); }
__device__ __forceinline__ float bfhi(unsigned u) { return __uint_as_float(u & 0xffff0000u); }

// ---------------------------------------------------------------------------
// prep: fused [xcvt | count | bfrag] via blockIdx range.
//   xcvt : x[N][128] fp32 -> xs[slice][N][32] bf16 (slice-major)
//   count: per-(sign,dst) edge counts (int atomics)
//   bfrag: weights -> MFMA B-fragment order
//          B_h[k][c] (K=256: rows 0-127 = w_l_h^T, 128-255 = w_r_h^T);
//          lane l holds B[k=32*kk+8*(l>>4)+j][c=16*nr+(l&15)].
// ---------------------------------------------------------------------------
__global__ __launch_bounds__(256) void prep_kernel(
    const float* __restrict__ x, const int* __restrict__ ei,
    const float* __restrict__ attr,
    const float* __restrict__ wpl, const float* __restrict__ wpr,
    const float* __restrict__ wnl, const float* __restrict__ wnr,
    unsigned short* __restrict__ xs, int* __restrict__ counts,
    unsigned short* __restrict__ Bfrag, int E, int N) {
    const int xblk = (N * 16 + 255) / 256;          // 3125
    const int cblk = (E + 255) / 256;               // 3125
    int b = blockIdx.x;
    if (b < xblk) {
        int i = b * 256 + threadIdx.x;
        if (i >= N * 16) return;
        int sl  = i / (N * 4);
        int rem = i - sl * N * 4;
        int n   = rem >> 2;
        int q   = rem & 3;
        const float4* xp = (const float4*)(x + (size_t)n * 128 + sl * FSL + q * 8);
        float4 v0 = xp[0];
        float4 v1 = xp[1];
        ushort8 o;
        o[0] = f2bf(v0.x); o[1] = f2bf(v0.y); o[2] = f2bf(v0.z); o[3] = f2bf(v0.w);
        o[4] = f2bf(v1.x); o[5] = f2bf(v1.y); o[6] = f2bf(v1.z); o[7] = f2bf(v1.w);
        *(ushort8*)(xs + ((size_t)sl * N + n) * FSL + q * 8) = o;
    } else if (b < xblk + cblk) {
        int e = (b - xblk) * 256 + threadIdx.x;
        if (e >= E) return;
        float w = attr[e];
        if (w == 0.f) return;
        int h = (w > 0.f) ? 0 : 1;
        int dst = ei[E + e];
        atomicAdd(&counts[h * N + dst], 1);
    } else {
        int tid = (b - xblk - cblk) * 256 + threadIdx.x;   // 0..8191
        int l  = tid & 63;
        int nr = (tid >> 6) & 7;
        int kk = (tid >> 9) & 7;
        int h  = tid >> 12;
        const float* wl = h ? wnl : wpl;
        const float* wr = h ? wnr : wpr;
        int c  = nr * 16 + (l & 15);
        int k0 = kk * 32 + (l >> 4) * 8;
        ushort8 o;
#pragma unroll
        for (int j = 0; j < 8; ++j) {
            int k = k0 + j;
            float v = (k < 128) ? wl[c * 128 + k] : wr[c * 128 + (k - 128)];
            o[j] = f2bf(v);
        }
        *(ushort8*)(Bfrag + (size_t)tid * 8) = o;
    }
}

// ---------------------------------------------------------------------------
// Exclusive scan over counts[0..n): chunked (1024/block).
// ---------------------------------------------------------------------------
__global__ __launch_bounds__(256) void scan_k1(
    const int* __restrict__ counts, int* __restrict__ partial, int n) {
    __shared__ int sd[256];
    int b = blockIdx.x, t = threadIdx.x;
    int idx = b * SCAN_CHUNK + t * 4;
    int s = 0;
#pragma unroll
    for (int j = 0; j < 4; ++j) { int i = idx + j; if (i < n) s += counts[i]; }
    sd[t] = s;
    __syncthreads();
    for (int off = 128; off > 0; off >>= 1) {
        if (t < off) sd[t] += sd[t + off];
        __syncthreads();
    }
    if (t == 0) partial[b] = sd[0];
}

__global__ __launch_bounds__(128) void scan_k2(
    const int* __restrict__ partial, int* __restrict__ base, int nb) {
    __shared__ int sd[128];
    int t = threadIdx.x;
    int own = (t < nb) ? partial[t] : 0;
    sd[t] = own;
    __syncthreads();
    for (int off = 1; off < 128; off <<= 1) {
        int v = (t >= off) ? sd[t - off] : 0;
        __syncthreads();
        sd[t] += v;
        __syncthreads();
    }
    if (t < nb) base[t] = sd[t] - own;   // exclusive
}

__global__ __launch_bounds__(256) void scan_k3(
    const int* __restrict__ counts, const int* __restrict__ base,
    int* __restrict__ offs, int* __restrict__ cursor, int n) {
    __shared__ int sd[256];
    int b = blockIdx.x, t = threadIdx.x;
    int idx = b * SCAN_CHUNK + t * 4;
    int c[4]; int s = 0;
#pragma unroll
    for (int j = 0; j < 4; ++j) { int i = idx + j; c[j] = (i < n) ? counts[i] : 0; s += c[j]; }
    sd[t] = s;
    __syncthreads();
    for (int off = 1; off < 256; off <<= 1) {   // inclusive Hillis-Steele
        int v = (t >= off) ? sd[t - off] : 0;
        __syncthreads();
        sd[t] += v;
        __syncthreads();
    }
    int run = base[b] + sd[t] - s;
#pragma unroll
    for (int j = 0; j < 4; ++j) {
        int i = idx + j;
        if (i < n) { offs[i] = run; cursor[i] = run; run += c[j]; }
    }
}

// ---------------------------------------------------------------------------
// CSR build pass 2: scatter packed meta = src (16b) | bf16(|w|) (16b).
// ---------------------------------------------------------------------------
__global__ __launch_bounds__(256) void scatter_kernel(
    const int* __restrict__ ei, const float* __restrict__ attr,
    int* __restrict__ cursor, unsigned* __restrict__ meta, int E, int N) {
    int e = blockIdx.x * 256 + threadIdx.x;
    if (e >= E) return;
    float w = attr[e];
    if (w == 0.f) return;
    int h = (w > 0.f) ? 0 : 1;
    int dst = ei[E + e];
    int slot = atomicAdd(&cursor[h * N + dst], 1);
    meta[slot] = (unsigned)ei[e] | ((unsigned)f2bf(fabsf(w)) << 16);
}

// ---------------------------------------------------------------------------
// Sliced aggregation. blockIdx%4 = slice (3.2 MB, L2-resident on its XCDs
// via round-robin dispatch). Each 8-lane group owns ONE (row, slice): lane
// fp holds features fp*4..fp*4+3 (8B); the group's edge list is walked with
// 4 independent partial accumulators (4 edges / 32 lines in flight per
// wave). No cross-lane reduction: group partials merge in-register, mean
// folds in, 8B bf16 store. 8 rows/wave, 32 rows/block, 12500 blocks.
// ---------------------------------------------------------------------------
__global__ __launch_bounds__(256) void agg_kernel(
    const unsigned short* __restrict__ xs, const unsigned* __restrict__ meta,
    const int* __restrict__ counts, const int* __restrict__ offs,
    unsigned short* __restrict__ mh, int twoN, int N) {
    const int slice = blockIdx.x & (NSLICE - 1);
    const int rblk  = blockIdx.x >> 2;
    const int wv    = threadIdx.x >> 6;
    const int lane  = threadIdx.x & 63;
    const int rloc  = lane >> 3;    // row within wave (0..7)
    const int fp    = lane & 7;     // feature quad within slice (0..7)
    const int r     = rblk * 32 + wv * 8 + rloc;
    if (r >= twoN) return;
    const unsigned short* xsl = xs + (size_t)slice * N * FSL;

    const int cn  = counts[r];
    const int beg = offs[r];
    f32x4 a0 = {0.f, 0.f, 0.f, 0.f}, a1 = a0, a2 = a0, a3 = a0;

    for (int j0 = 0; j0 < cn; j0 += 4) {
        unsigned m0 = meta[beg + j0];
        unsigned m1 = (j0 + 1 < cn) ? meta[beg + j0 + 1] : 0u;
        unsigned m2 = (j0 + 2 < cn) ? meta[beg + j0 + 2] : 0u;
        unsigned m3 = (j0 + 3 < cn) ? meta[beg + j0 + 3] : 0u;
        uint2 v0 = *(const uint2*)(xsl + (size_t)(m0 & 0xffffu) * FSL + fp * 4);
        uint2 v1 = *(const uint2*)(xsl + (size_t)(m1 & 0xffffu) * FSL + fp * 4);
        uint2 v2 = *(const uint2*)(xsl + (size_t)(m2 & 0xffffu) * FSL + fp * 4);
        uint2 v3 = *(const uint2*)(xsl + (size_t)(m3 & 0xffffu) * FSL + fp * 4);
        const float w0 = bfhi(m0), w1 = bfhi(m1), w2 = bfhi(m2), w3 = bfhi(m3);
        a0[0] = fmaf(bflo(v0.x), w0, a0[0]); a0[1] = fmaf(bfhi(v0.x), w0, a0[1]);
        a0[2] = fmaf(bflo(v0.y), w0, a0[2]); a0[3] = fmaf(bfhi(v0.y), w0, a0[3]);
        a1[0] = fmaf(bflo(v1.x), w1, a1[0]); a1[1] = fmaf(bfhi(v1.x), w1, a1[1]);
        a1[2] = fmaf(bflo(v1.y), w1, a1[2]); a1[3] = fmaf(bfhi(v1.y), w1, a1[3]);
        a2[0] = fmaf(bflo(v2.x), w2, a2[0]); a2[1] = fmaf(bfhi(v2.x), w2, a2[1]);
        a2[2] = fmaf(bflo(v2.y), w2, a2[2]); a2[3] = fmaf(bfhi(v2.y), w2, a2[3]);
        a3[0] = fmaf(bflo(v3.x), w3, a3[0]); a3[1] = fmaf(bfhi(v3.x), w3, a3[1]);
        a3[2] = fmaf(bflo(v3.y), w3, a3[2]); a3[3] = fmaf(bfhi(v3.y), w3, a3[3]);
    }

    const float inv = 1.f / fmaxf((float)cn, 1.f);
    const f32x4 s = (a0 + a1) + (a2 + a3);
    uint2 p;
    p.x = (unsigned)f2bf(s[0] * inv) | ((unsigned)f2bf(s[1] * inv) << 16);
    p.y = (unsigned)f2bf(s[2] * inv) | ((unsigned)f2bf(s[3] * inv) << 16);
    *(uint2*)(mh + (size_t)r * 128 + slice * FSL + fp * 4) = p;
}

// ---------------------------------------------------------------------------
// Output GEMM via MFMA. grid = (ceil(N/128), 2), block 256 (4 waves).
// K=256: kk 0..3 read mean_h (row-major mh), kk 4..7 read x from the sliced
// xs layout (8-feature A-chunks never cross a 32-feature slice). B-frags
// from fragment-packed global (L2-resident). No LDS, no barriers.
// ---------------------------------------------------------------------------
__global__ __launch_bounds__(256) void out_mfma(
    const unsigned short* __restrict__ mh, const unsigned short* __restrict__ xs,
    const unsigned short* __restrict__ Bfrag,
    const float* __restrict__ bpos, const float* __restrict__ bneg,
    float* __restrict__ out, int N) {
    const int h  = blockIdx.y;
    const int l  = threadIdx.x & 63;
    const int wv = threadIdx.x >> 6;
    const int m0 = blockIdx.x * 128 + wv * 32;
    const int lm = l & 15;
    const int lk = l >> 4;

    const unsigned short* Am = mh + (size_t)h * N * 128;
    const bf16x8* Bf = (const bf16x8*)Bfrag + (size_t)h * 4096;

    f32x4 acc[2][8];
#pragma unroll
    for (int mr = 0; mr < 2; ++mr)
#pragma unroll
        for (int nr = 0; nr < 8; ++nr)
            acc[mr][nr] = (f32x4){0.f, 0.f, 0.f, 0.f};

    int r0 = m0 + lm;       if (r0 > N - 1) r0 = N - 1;
    int r1 = m0 + 16 + lm;  if (r1 > N - 1) r1 = N - 1;

#pragma unroll
    for (int kk = 0; kk < 8; ++kk) {
        bf16x8 a0, a1;
        if (kk < 4) {
            const int kloc = kk * 32 + lk * 8;
            a0 = *(const bf16x8*)(Am + (size_t)r0 * 128 + kloc);
            a1 = *(const bf16x8*)(Am + (size_t)r1 * 128 + kloc);
        } else {
            const size_t sbase = (size_t)(kk & 3) * N * FSL + lk * 8;
            a0 = *(const bf16x8*)(xs + sbase + (size_t)r0 * FSL);
            a1 = *(const bf16x8*)(xs + sbase + (size_t)r1 * FSL);
        }
        const bf16x8* bk = Bf + kk * 8 * 64;
#pragma unroll
        for (int nr = 0; nr < 8; ++nr) {
            bf16x8 b = bk[nr * 64 + l];
            acc[0][nr] = __builtin_amdgcn_mfma_f32_16x16x32_bf16(a0, b, acc[0][nr], 0, 0, 0);
            acc[1][nr] = __builtin_amdgcn_mfma_f32_16x16x32_bf16(a1, b, acc[1][nr], 0, 0, 0);
        }
    }

    const float* bb = (h == 0) ? bpos : bneg;
#pragma unroll
    for (int nr = 0; nr < 8; ++nr) {
        const float bc = bb[nr * 16 + lm];
#pragma unroll
        for (int mr = 0; mr < 2; ++mr) {
#pragma unroll
            for (int rr = 0; rr < 4; ++rr) {
                const int row = m0 + mr * 16 + lk * 4 + rr;
                if (row < N)
                    out[(size_t)row * 256 + h * 128 + nr * 16 + lm] =
                        fmaxf(acc[mr][nr][rr] + bc, 0.f);
            }
        }
    }
}

// ---------------------------------------------------------------------------
extern "C" void kernel_launch(void* const* d_in, const int* in_sizes, int n_in,
                              void* d_out, int out_size, void* d_ws, size_t ws_size,
                              hipStream_t stream) {
    const float* x    = (const float*)d_in[0];
    const int*   ei   = (const int*)d_in[1];
    const float* attr = (const float*)d_in[2];
    const float* wpl  = (const float*)d_in[3];
    const float* wpr  = (const float*)d_in[4];
    const float* bpos = (const float*)d_in[5];
    const float* wnl  = (const float*)d_in[6];
    const float* wnr  = (const float*)d_in[7];
    const float* bneg = (const float*)d_in[8];
    float* out = (float*)d_out;

    const int N = in_sizes[0] / 128;   // 50000
    const int E = in_sizes[2];         // 800000
    const int twoN = 2 * N;

    // Workspace layout:
    //   mh     ushort [2N][128]      bf16 per-sign means (already divided)
    //   xs     ushort [4][N][32]     bf16 features, slice-major
    //   Bfrag  ushort [2][4096][8]   fragment-packed weights
    //   meta   u32    [E]            packed (src | bf16|w|<<16) CSR records
    //   counts,offs,cursor int [2N]
    //   partial,base int [128]
    unsigned short* mh    = (unsigned short*)d_ws;
    unsigned short* xs    = mh + (size_t)twoN * 128;
    unsigned short* Bfrag = xs + (size_t)N * 128;
    unsigned* meta = (unsigned*)(Bfrag + 65536);
    int* counts  = (int*)(meta + E);
    int* offs    = counts + twoN;
    int* cursor  = offs + twoN;
    int* partial = cursor + twoN;
    int* sbase   = partial + 128;

    const int nchunk = (twoN + SCAN_CHUNK - 1) / SCAN_CHUNK;   // 98 (<=128)
    const int xblk = (N * 16 + 255) / 256;                     // 3125
    const int cblk = (E + 255) / 256;                          // 3125

    hipMemsetAsync(counts, 0, (size_t)twoN * sizeof(int), stream);

    prep_kernel<<<xblk + cblk + 32, 256, 0, stream>>>(
        x, ei, attr, wpl, wpr, wnl, wnr, xs, counts, Bfrag, E, N);
    scan_k1<<<nchunk, 256, 0, stream>>>(counts, partial, twoN);
    scan_k2<<<1, 128, 0, stream>>>(partial, sbase, nchunk);
    scan_k3<<<nchunk, 256, 0, stream>>>(counts, sbase, offs, cursor, twoN);
    scatter_kernel<<<cblk, 256, 0, stream>>>(ei, attr, cursor, meta, E, N);
    agg_kernel<<<((twoN + 31) / 32) * NSLICE, 256, 0, stream>>>(
        xs, meta, counts, offs, mh, twoN, N);
    out_mfma<<<dim3((N + 127) / 128, 2), 256, 0, stream>>>(
        mh, xs, Bfrag, bpos, bneg, out, N);
}

// Round 8
// 161.893 us; speedup vs baseline: 1.7835x; 1.0316x over previous
//
#include <hip/hip_runtime.h>
#include <hip/hip_bf16.h>

// N = 50000, E = 800000, F_IN = F_OUT = 128.
// Pipeline: prep (bf16 slice-cvt + edge-record pack + counts + weight
// frag-pack) -> scan -> XCD-bucketed scatter (writes L2-local per XCD) ->
// XCD-sliced aggregation (8 lanes x 8B = one 64B slice-row per edge) ->
// MFMA bf16 GEMM with fragment-packed weights.

#define SCAN_CHUNK 1024
#define NSLICE 4     // feature slices (32 features = 64 B per node per slice)
#define FSL 32       // features per slice
#define NBUCKET 8    // scatter row-buckets (one per XCD via blockIdx&7)

typedef __attribute__((ext_vector_type(8))) short bf16x8;
typedef __attribute__((ext_vector_type(8))) unsigned short ushort8;
typedef __attribute__((ext_vector_type(4))) float f32x4;

__device__ __forceinline__ unsigned short f2bf(float f) {
    unsigned int u = __float_as_uint(f);
    unsigned int r = (u + 0x7fffu + ((u >> 16) & 1u)) >> 16;
    return (unsigned short)r;
}
__device__ __forceinline__ float bflo(unsigned u) { return __uint_as_float(u << 16); }
__device__ __forceinline__ float bfhi(unsigned u) { return __uint_as_float(u & 0xffff0000u); }

// ---------------------------------------------------------------------------
// prep: fused [xcvt | count+pack | bfrag] via blockIdx range.
//   xcvt : x[N][128] fp32 -> xs[slice][N][32] bf16 (slice-major)
//   count: per-(sign,dst) edge counts (int atomics) + packed edge records
//          epk[e] = { row | valid<<31 , src | bf16(|w|)<<16 }
//   bfrag: weights -> MFMA B-fragment order (B_h[k][c], K=256:
//          rows 0-127 = w_l_h^T, 128-255 = w_r_h^T; lane l holds
//          B[k=32*kk+8*(l>>4)+j][c=16*nr+(l&15)]).
// ---------------------------------------------------------------------------
__global__ __launch_bounds__(256) void prep_kernel(
    const float* __restrict__ x, const int* __restrict__ ei,
    const float* __restrict__ attr,
    const float* __restrict__ wpl, const float* __restrict__ wpr,
    const float* __restrict__ wnl, const float* __restrict__ wnr,
    unsigned short* __restrict__ xs, int* __restrict__ counts,
    uint2* __restrict__ epk, unsigned short* __restrict__ Bfrag,
    int E, int N) {
    const int xblk = (N * 16 + 255) / 256;          // 3125
    const int cblk = (E + 255) / 256;               // 3125
    int b = blockIdx.x;
    if (b < xblk) {
        int i = b * 256 + threadIdx.x;
        if (i >= N * 16) return;
        int sl  = i / (N * 4);
        int rem = i - sl * N * 4;
        int n   = rem >> 2;
        int q   = rem & 3;
        const float4* xp = (const float4*)(x + (size_t)n * 128 + sl * FSL + q * 8);
        float4 v0 = xp[0];
        float4 v1 = xp[1];
        ushort8 o;
        o[0] = f2bf(v0.x); o[1] = f2bf(v0.y); o[2] = f2bf(v0.z); o[3] = f2bf(v0.w);
        o[4] = f2bf(v1.x); o[5] = f2bf(v1.y); o[6] = f2bf(v1.z); o[7] = f2bf(v1.w);
        *(ushort8*)(xs + ((size_t)sl * N + n) * FSL + q * 8) = o;
    } else if (b < xblk + cblk) {
        int e = (b - xblk) * 256 + threadIdx.x;
        if (e >= E) return;
        float w = attr[e];
        int src = ei[e];
        int dst = ei[E + e];
        int h = (w > 0.f) ? 0 : 1;
        unsigned valid = (w != 0.f) ? 0x80000000u : 0u;
        uint2 rec;
        rec.x = (unsigned)(h * N + dst) | valid;
        rec.y = (unsigned)src | ((unsigned)f2bf(fabsf(w)) << 16);
        epk[e] = rec;
        if (valid) atomicAdd(&counts[h * N + dst], 1);
    } else {
        int tid = (b - xblk - cblk) * 256 + threadIdx.x;   // 0..8191
        int l  = tid & 63;
        int nr = (tid >> 6) & 7;
        int kk = (tid >> 9) & 7;
        int h  = tid >> 12;
        const float* wl = h ? wnl : wpl;
        const float* wr = h ? wnr : wpr;
        int c  = nr * 16 + (l & 15);
        int k0 = kk * 32 + (l >> 4) * 8;
        ushort8 o;
#pragma unroll
        for (int j = 0; j < 8; ++j) {
            int k = k0 + j;
            float v = (k < 128) ? wl[c * 128 + k] : wr[c * 128 + (k - 128)];
            o[j] = f2bf(v);
        }
        *(ushort8*)(Bfrag + (size_t)tid * 8) = o;
    }
}

// ---------------------------------------------------------------------------
// Exclusive scan over counts[0..n): chunked (1024/block).
// ---------------------------------------------------------------------------
__global__ __launch_bounds__(256) void scan_k1(
    const int* __restrict__ counts, int* __restrict__ partial, int n) {
    __shared__ int sd[256];
    int b = blockIdx.x, t = threadIdx.x;
    int idx = b * SCAN_CHUNK + t * 4;
    int s = 0;
#pragma unroll
    for (int j = 0; j < 4; ++j) { int i = idx + j; if (i < n) s += counts[i]; }
    sd[t] = s;
    __syncthreads();
    for (int off = 128; off > 0; off >>= 1) {
        if (t < off) sd[t] += sd[t + off];
        __syncthreads();
    }
    if (t == 0) partial[b] = sd[0];
}

__global__ __launch_bounds__(128) void scan_k2(
    const int* __restrict__ partial, int* __restrict__ base, int nb) {
    __shared__ int sd[128];
    int t = threadIdx.x;
    int own = (t < nb) ? partial[t] : 0;
    sd[t] = own;
    __syncthreads();
    for (int off = 1; off < 128; off <<= 1) {
        int v = (t >= off) ? sd[t - off] : 0;
        __syncthreads();
        sd[t] += v;
        __syncthreads();
    }
    if (t < nb) base[t] = sd[t] - own;   // exclusive
}

__global__ __launch_bounds__(256) void scan_k3(
    const int* __restrict__ counts, const int* __restrict__ base,
    int* __restrict__ offs, int* __restrict__ cursor, int n) {
    __shared__ int sd[256];
    int b = blockIdx.x, t = threadIdx.x;
    int idx = b * SCAN_CHUNK + t * 4;
    int c[4]; int s = 0;
#pragma unroll
    for (int j = 0; j < 4; ++j) { int i = idx + j; c[j] = (i < n) ? counts[i] : 0; s += c[j]; }
    sd[t] = s;
    __syncthreads();
    for (int off = 1; off < 256; off <<= 1) {   // inclusive Hillis-Steele
        int v = (t >= off) ? sd[t - off] : 0;
        __syncthreads();
        sd[t] += v;
        __syncthreads();
    }
    int run = base[b] + sd[t] - s;
#pragma unroll
    for (int j = 0; j < 4; ++j) {
        int i = idx + j;
        if (i < n) { offs[i] = run; cursor[i] = run; run += c[j]; }
    }
}

// ---------------------------------------------------------------------------
// CSR scatter, XCD-bucketed. grid = NBUCKET * ceil(E/256); block handles
// (bucket = blockIdx&7, chunk = blockIdx>>3). Rows are split into 8
// contiguous ranges; CSR offsets are monotone, so bucket b's meta slots
// form one contiguous ~E/8*4B region. All blocks of bucket b land on XCD b
// (round-robin dispatch), so cursor atomics and meta writes are L2-local
// and merge into full lines before writeback. Reads of epk are L3-served.
// ---------------------------------------------------------------------------
__global__ __launch_bounds__(256) void scatter_kernel(
    const uint2* __restrict__ epk, int* __restrict__ cursor,
    unsigned* __restrict__ meta, int E, int Q) {
    const int bucket = blockIdx.x & (NBUCKET - 1);
    const int e = (blockIdx.x >> 3) * 256 + threadIdx.x;
    if (e >= E) return;
    uint2 rec = epk[e];
    if (!(rec.x & 0x80000000u)) return;      // w == 0: excluded everywhere
    const int r = (int)(rec.x & 0x7fffffffu);
    const int rlo = bucket * Q;
    if (r < rlo || r >= rlo + Q) return;     // not this XCD's row range
    int slot = atomicAdd(&cursor[r], 1);
    meta[slot] = rec.y;
}

// ---------------------------------------------------------------------------
// Sliced aggregation. blockIdx%4 = slice (3.2 MB, L2-resident on its XCDs
// via round-robin dispatch). Each 8-lane group owns ONE (row, slice): lane
// fp holds features fp*4..fp*4+3 (8B); the group's edge list is walked with
// 4 independent partial accumulators. No cross-lane reduction. 8 rows/wave.
// ---------------------------------------------------------------------------
__global__ __launch_bounds__(256) void agg_kernel(
    const unsigned short* __restrict__ xs, const unsigned* __restrict__ meta,
    const int* __restrict__ counts, const int* __restrict__ offs,
    unsigned short* __restrict__ mh, int twoN, int N) {
    const int slice = blockIdx.x & (NSLICE - 1);
    const int rblk  = blockIdx.x >> 2;
    const int wv    = threadIdx.x >> 6;
    const int lane  = threadIdx.x & 63;
    const int rloc  = lane >> 3;    // row within wave (0..7)
    const int fp    = lane & 7;     // feature quad within slice (0..7)
    const int r     = rblk * 32 + wv * 8 + rloc;
    if (r >= twoN) return;
    const unsigned short* xsl = xs + (size_t)slice * N * FSL;

    const int cn  = counts[r];
    const int beg = offs[r];
    f32x4 a0 = {0.f, 0.f, 0.f, 0.f}, a1 = a0, a2 = a0, a3 = a0;

    for (int j0 = 0; j0 < cn; j0 += 4) {
        unsigned m0 = meta[beg + j0];
        unsigned m1 = (j0 + 1 < cn) ? meta[beg + j0 + 1] : 0u;
        unsigned m2 = (j0 + 2 < cn) ? meta[beg + j0 + 2] : 0u;
        unsigned m3 = (j0 + 3 < cn) ? meta[beg + j0 + 3] : 0u;
        uint2 v0 = *(const uint2*)(xsl + (size_t)(m0 & 0xffffu) * FSL + fp * 4);
        uint2 v1 = *(const uint2*)(xsl + (size_t)(m1 & 0xffffu) * FSL + fp * 4);
        uint2 v2 = *(const uint2*)(xsl + (size_t)(m2 & 0xffffu) * FSL + fp * 4);
        uint2 v3 = *(const uint2*)(xsl + (size_t)(m3 & 0xffffu) * FSL + fp * 4);
        const float w0 = bfhi(m0), w1 = bfhi(m1), w2 = bfhi(m2), w3 = bfhi(m3);
        a0[0] = fmaf(bflo(v0.x), w0, a0[0]); a0[1] = fmaf(bfhi(v0.x), w0, a0[1]);
        a0[2] = fmaf(bflo(v0.y), w0, a0[2]); a0[3] = fmaf(bfhi(v0.y), w0, a0[3]);
        a1[0] = fmaf(bflo(v1.x), w1, a1[0]); a1[1] = fmaf(bfhi(v1.x), w1, a1[1]);
        a1[2] = fmaf(bflo(v1.y), w1, a1[2]); a1[3] = fmaf(bfhi(v1.y), w1, a1[3]);
        a2[0] = fmaf(bflo(v2.x), w2, a2[0]); a2[1] = fmaf(bfhi(v2.x), w2, a2[1]);
        a2[2] = fmaf(bflo(v2.y), w2, a2[2]); a2[3] = fmaf(bfhi(v2.y), w2, a2[3]);
        a3[0] = fmaf(bflo(v3.x), w3, a3[0]); a3[1] = fmaf(bfhi(v3.x), w3, a3[1]);
        a3[2] = fmaf(bflo(v3.y), w3, a3[2]); a3[3] = fmaf(bfhi(v3.y), w3, a3[3]);
    }

    const float inv = 1.f / fmaxf((float)cn, 1.f);
    const f32x4 s = (a0 + a1) + (a2 + a3);
    uint2 p;
    p.x = (unsigned)f2bf(s[0] * inv) | ((unsigned)f2bf(s[1] * inv) << 16);
    p.y = (unsigned)f2bf(s[2] * inv) | ((unsigned)f2bf(s[3] * inv) << 16);
    *(uint2*)(mh + (size_t)r * 128 + slice * FSL + fp * 4) = p;
}

// ---------------------------------------------------------------------------
// Output GEMM via MFMA. grid = (ceil(N/128), 2), block 256 (4 waves).
// K=256: kk 0..3 read mean_h (row-major mh), kk 4..7 read x from the sliced
// xs layout (8-feature A-chunks never cross a 32-feature slice). B-frags
// from fragment-packed global (L2-resident). No LDS, no barriers.
// ---------------------------------------------------------------------------
__global__ __launch_bounds__(256) void out_mfma(
    const unsigned short* __restrict__ mh, const unsigned short* __restrict__ xs,
    const unsigned short* __restrict__ Bfrag,
    const float* __restrict__ bpos, const float* __restrict__ bneg,
    float* __restrict__ out, int N) {
    const int h  = blockIdx.y;
    const int l  = threadIdx.x & 63;
    const int wv = threadIdx.x >> 6;
    const int m0 = blockIdx.x * 128 + wv * 32;
    const int lm = l & 15;
    const int lk = l >> 4;

    const unsigned short* Am = mh + (size_t)h * N * 128;
    const bf16x8* Bf = (const bf16x8*)Bfrag + (size_t)h * 4096;

    f32x4 acc[2][8];
#pragma unroll
    for (int mr = 0; mr < 2; ++mr)
#pragma unroll
        for (int nr = 0; nr < 8; ++nr)
            acc[mr][nr] = (f32x4){0.f, 0.f, 0.f, 0.f};

    int r0 = m0 + lm;       if (r0 > N - 1) r0 = N - 1;
    int r1 = m0 + 16 + lm;  if (r1 > N - 1) r1 = N - 1;

#pragma unroll
    for (int kk = 0; kk < 8; ++kk) {
        bf16x8 a0, a1;
        if (kk < 4) {
            const int kloc = kk * 32 + lk * 8;
            a0 = *(const bf16x8*)(Am + (size_t)r0 * 128 + kloc);
            a1 = *(const bf16x8*)(Am + (size_t)r1 * 128 + kloc);
        } else {
            const size_t sbase = (size_t)(kk & 3) * N * FSL + lk * 8;
            a0 = *(const bf16x8*)(xs + sbase + (size_t)r0 * FSL);
            a1 = *(const bf16x8*)(xs + sbase + (size_t)r1 * FSL);
        }
        const bf16x8* bk = Bf + kk * 8 * 64;
#pragma unroll
        for (int nr = 0; nr < 8; ++nr) {
            bf16x8 b = bk[nr * 64 + l];
            acc[0][nr] = __builtin_amdgcn_mfma_f32_16x16x32_bf16(a0, b, acc[0][nr], 0, 0, 0);
            acc[1][nr] = __builtin_amdgcn_mfma_f32_16x16x32_bf16(a1, b, acc[1][nr], 0, 0, 0);
        }
    }

    const float* bb = (h == 0) ? bpos : bneg;
#pragma unroll
    for (int nr = 0; nr < 8; ++nr) {
        const float bc = bb[nr * 16 + lm];
#pragma unroll
        for (int mr = 0; mr < 2; ++mr) {
#pragma unroll
            for (int rr = 0; rr < 4; ++rr) {
                const int row = m0 + mr * 16 + lk * 4 + rr;
                if (row < N)
                    out[(size_t)row * 256 + h * 128 + nr * 16 + lm] =
                        fmaxf(acc[mr][nr][rr] + bc, 0.f);
            }
        }
    }
}

// ---------------------------------------------------------------------------
extern "C" void kernel_launch(void* const* d_in, const int* in_sizes, int n_in,
                              void* d_out, int out_size, void* d_ws, size_t ws_size,
                              hipStream_t stream) {
    const float* x    = (const float*)d_in[0];
    const int*   ei   = (const int*)d_in[1];
    const float* attr = (const float*)d_in[2];
    const float* wpl  = (const float*)d_in[3];
    const float* wpr  = (const float*)d_in[4];
    const float* bpos = (const float*)d_in[5];
    const float* wnl  = (const float*)d_in[6];
    const float* wnr  = (const float*)d_in[7];
    const float* bneg = (const float*)d_in[8];
    float* out = (float*)d_out;

    const int N = in_sizes[0] / 128;   // 50000
    const int E = in_sizes[2];         // 800000
    const int twoN = 2 * N;
    const int Q = (twoN + NBUCKET - 1) / NBUCKET;   // rows per bucket

    // Workspace layout:
    //   mh     ushort [2N][128]      bf16 per-sign means (already divided)
    //   xs     ushort [4][N][32]     bf16 features, slice-major
    //   Bfrag  ushort [2][4096][8]   fragment-packed weights
    //   epk    uint2  [E]            packed edge records {row|valid, src|w}
    //   meta   u32    [E]            CSR records (src | bf16|w|<<16)
    //   counts,offs,cursor int [2N]
    //   partial,base int [128]
    unsigned short* mh    = (unsigned short*)d_ws;
    unsigned short* xs    = mh + (size_t)twoN * 128;
    unsigned short* Bfrag = xs + (size_t)N * 128;
    uint2* epk   = (uint2*)(Bfrag + 65536);
    unsigned* meta = (unsigned*)(epk + E);
    int* counts  = (int*)(meta + E);
    int* offs    = counts + twoN;
    int* cursor  = offs + twoN;
    int* partial = cursor + twoN;
    int* sbase   = partial + 128;

    const int nchunk = (twoN + SCAN_CHUNK - 1) / SCAN_CHUNK;   // 98 (<=128)
    const int xblk = (N * 16 + 255) / 256;                     // 3125
    const int cblk = (E + 255) / 256;                          // 3125

    hipMemsetAsync(counts, 0, (size_t)twoN * sizeof(int), stream);

    prep_kernel<<<xblk + cblk + 32, 256, 0, stream>>>(
        x, ei, attr, wpl, wpr, wnl, wnr, xs, counts, epk, Bfrag, E, N);
    scan_k1<<<nchunk, 256, 0, stream>>>(counts, partial, twoN);
    scan_k2<<<1, 128, 0, stream>>>(partial, sbase, nchunk);
    scan_k3<<<nchunk, 256, 0, stream>>>(counts, sbase, offs, cursor, twoN);
    scatter_kernel<<<NBUCKET * cblk, 256, 0, stream>>>(epk, cursor, meta, E, Q);
    agg_kernel<<<((twoN + 31) / 32) * NSLICE, 256, 0, stream>>>(
        xs, meta, counts, offs, mh, twoN, N);
    out_mfma<<<dim3((N + 127) / 128, 2), 256, 0, stream>>>(
        mh, xs, Bfrag, bpos, bneg, out, N);
}